// Round 1
// baseline (953.810 us; speedup 1.0000x reference)
//
#include <hip/hip_runtime.h>

// CRF backward decode: T=256 sequential steps, B=4096 independent chains,
// NUM_TAGS=128. Round 1: sparse latency-bound baseline — 1 thread per chain,
// dependent gather on bp drives the chain; tags gather + store hang off it.
// Purpose: correctness anchor + measure real per-step gather latency and
// HBM fetch granularity (FETCH_SIZE) to choose the round-2 structure.

#define T_STEPS 256
#define BATCH   4096
#define NTAGS   128

__global__ __launch_bounds__(64) void crf_chain_kernel(
    const float* __restrict__ tags,   // (T, B, NTAGS) f32
    const int*   __restrict__ bp,     // (T, B, NTAGS) i32, values in [0,128)
    const int*   __restrict__ init,   // (B,) i32
    float*       __restrict__ out)    // (T, B, 1) f32
{
    const int b = blockIdx.x * blockDim.x + threadIdx.x;
    if (b >= BATCH) return;

    int s = init[b];
    const size_t row_b = (size_t)b * NTAGS;

    #pragma unroll 1
    for (int t = 0; t < T_STEPS; ++t) {
        const size_t off = (size_t)t * ((size_t)BATCH * NTAGS) + row_b + (size_t)s;
        // tags load is off the critical path; bp load feeds next iteration.
        const float v  = tags[off];
        const int   ns = bp[off];
        out[(size_t)t * BATCH + b] = v;   // coalesced across lanes (consecutive b)
        s = ns;
    }
}

extern "C" void kernel_launch(void* const* d_in, const int* in_sizes, int n_in,
                              void* d_out, int out_size, void* d_ws, size_t ws_size,
                              hipStream_t stream) {
    const float* tags = (const float*)d_in[0];
    const int*   bp   = (const int*)d_in[1];
    const int*   init = (const int*)d_in[2];
    float*       out  = (float*)d_out;

    // 64 blocks x 64 threads = 4096 threads (one per chain), spread over 64 CUs.
    crf_chain_kernel<<<dim3(BATCH / 64), dim3(64), 0, stream>>>(tags, bp, init, out);
}